// Round 7
// baseline (211.892 us; speedup 1.0000x reference)
//
#include <hip/hip_runtime.h>

// TriangleLinear: out[b][8191-r] = bias[r] + sum_{c>=max(0,r-4)} W_packed[...] * x[b][c]
// HBM floor: 134.4 MB packed-weight stream read once => ~21 us kernel.
//
// Measurement model: dur_us ~= kernel + ~156 us harness re-poison fills (rocprof
// top-5 shows only 77-80us fillBufferAligned; our kernel dispatch < 77us).
//   R0 scalar w + nt, simple loop:    ~41 us (197)
//   R2 scalar strided, no-nt:         ~52 us (208)  (no-nt: w evicts x from L2)
//   R3 scalar + manual dbuf, no-nt:   ~51 us (207)  (dbuf = VGPR/schedule poison)
//   R5 dwordx4 + nt + manual dbuf:    ~54 us (210)
//   R6 dwordx4 + nt, simple loop:     ~41 us (197)  == R0 exactly
// R6's neutrality kills the VMEM-issue/line-touch model (4x fewer w instrs, no
// change). Remaining constraint: latency hiding at 16 waves/CU — the 35 KB
// reduction LDS caps residency at 4 blocks/CU; waves serialize {issue loads ->
// ~900cyc nt-HBM stall -> 256cyc FMA} with too few peers to cover the stalls
// (3.3 TB/s vs fills' 6.8).
//
// R7: in-register epilogue. 6x __shfl_xor butterfly per (row,batch) sum (192
// shfl+add once per thread), cross-wave combine via 512 B LDS (was 35 KB).
// LDS no longer binds -> __launch_bounds__(256,5): VGPR cap 102 vs ~95 live,
// 5 blocks/CU = 20 waves/CU (+25% latency hiding / in-flight bytes).
// Main loop byte-identical to R6. Predicted kernel ~33-36 us => dur_us ~190.

constexpr int N = 8192;      // N_IN == N_OUT
constexpr int BATCH = 8;
constexpr int ROWS = 4;      // rows per block: x loads shared across rows in registers
constexpr int THREADS = 256;
constexpr int VEC = 4;       // columns per thread (packed: float4 x loads)
constexpr int TILE = THREADS * VEC;  // 1024 columns per block-iteration

typedef float f32x4 __attribute__((ext_vector_type(4)));

__global__ __launch_bounds__(THREADS, 5)
void tri_linear_kernel(const float* __restrict__ x,
                       const float* __restrict__ w,
                       const float* __restrict__ bias,
                       float* __restrict__ out) {
  const int t = threadIdx.x;
  const int r0 = blockIdx.x * ROWS;

  // Per-row triangular start column and packed-row base pointers (uniform -> SGPR).
  int c0[ROWS];
  const float* wrow[ROWS];
#pragma unroll
  for (int i = 0; i < ROWS; ++i) {
    const int r = r0 + i;
    c0[i] = (r > 4) ? (r - 4) : 0;
    // off(r) = 8192*r - (r-5)(r-4)/2 for r>=5, else 8192*r. (off(8192)=33,591,286 = nW)
    long long off = (r <= 5)
        ? (long long)r * N
        : (long long)r * N - ((long long)(r - 5) * (long long)(r - 4)) / 2;
    wrow[i] = w + (off - (long long)c0[i]);   // wrow[i][c] valid for c in [c0[i], N)
  }
  const int cbA = c0[0] & ~(TILE - 1);        // c0[0] == min c0 of this block's rows
  // c0[0] = r0-4 is a multiple of 4, so c0[i] <= c0[0]+3 <= cbA+1023: every row's
  // triangular start falls inside the edge tile; main loop needs no predicate.

  float acc[ROWS][BATCH];
#pragma unroll
  for (int i = 0; i < ROWS; ++i)
#pragma unroll
    for (int b = 0; b < BATCH; ++b) acc[i][b] = 0.0f;

  const int c4 = VEC * t;   // this thread's packed column offset within a tile

  // ---- Edge tile [cbA, cbA+TILE): predicated on the triangular boundary ----
  {
    const int c = cbA + c4;
    float4 xv[BATCH];
#pragma unroll
    for (int b = 0; b < BATCH; ++b)
      xv[b] = *(const float4*)(x + b * N + c);
#pragma unroll
    for (int i = 0; i < ROWS; ++i) {
#pragma unroll
      for (int j = 0; j < VEC; ++j) {
        const int cj = c + j;
        const float wv = (cj >= c0[i]) ? __builtin_nontemporal_load(wrow[i] + cj)
                                       : 0.0f;
        const float* xe;
#pragma unroll
        for (int b = 0; b < BATCH; ++b) {
          xe = reinterpret_cast<const float*>(&xv[b]);
          acc[i][b] = fmaf(wv, xe[j], acc[i][b]);
        }
      }
    }
  }

  // ---- Main loop: predicate-free; w as 16B nt vector loads; NO manual dbuf ----
  // (R3/R5: manual double-buffer costs ~10us. Compiler pipelines this itself.)
  for (int cb = cbA + TILE; cb < N; cb += TILE) {
    const int c = cb + c4;
    float4 xv[BATCH];
#pragma unroll
    for (int b = 0; b < BATCH; ++b)
      xv[b] = *(const float4*)(x + b * N + c);   // L2-hot
    f32x4 wv4[ROWS];
#pragma unroll
    for (int i = 0; i < ROWS; ++i)
      wv4[i] = __builtin_nontemporal_load(
          reinterpret_cast<const f32x4*>(wrow[i] + c));  // 4B-aligned x4: HW
                                                         // unaligned mode (R5-verified)
#pragma unroll
    for (int i = 0; i < ROWS; ++i)
#pragma unroll
      for (int j = 0; j < VEC; ++j) {
        const float* xe;
#pragma unroll
        for (int b = 0; b < BATCH; ++b) {
          xe = reinterpret_cast<const float*>(&xv[b]);
          acc[i][b] = fmaf(wv4[i][j], xe[j], acc[i][b]);
        }
      }
  }

  // ---- Epilogue: in-register wave butterfly, then 512 B cross-wave combine ----
  // 6 shfl_xor steps reduce each (row,batch) sum across the 64-lane wave; every
  // lane ends with the wave total (static indexing only — no scratch).
#pragma unroll
  for (int i = 0; i < ROWS; ++i)
#pragma unroll
    for (int b = 0; b < BATCH; ++b) {
      float v = acc[i][b];
      v += __shfl_xor(v, 1);
      v += __shfl_xor(v, 2);
      v += __shfl_xor(v, 4);
      v += __shfl_xor(v, 8);
      v += __shfl_xor(v, 16);
      v += __shfl_xor(v, 32);
      acc[i][b] = v;
    }

  __shared__ float part[THREADS / 64][ROWS * BATCH];  // 4 x 32 floats = 512 B
  const int wv = t >> 6;
  if ((t & 63) == 0) {
#pragma unroll
    for (int i = 0; i < ROWS; ++i)
#pragma unroll
      for (int b = 0; b < BATCH; ++b)
        part[wv][i * BATCH + b] = acc[i][b];
  }
  __syncthreads();

  if (t < ROWS * BATCH) {
    // lanes 0..31 read part[g][t]: addr g*32+t -> bank t, conflict-free.
    float total = part[0][t] + part[1][t] + part[2][t] + part[3][t];
    const int i = t >> 3, b = t & 7;   // t == i*BATCH + b
    const int r = r0 + i;
    out[b * N + (N - 1 - r)] = total + bias[r];  // last-dim flip + bias
  }
}

extern "C" void kernel_launch(void* const* d_in, const int* in_sizes, int n_in,
                              void* d_out, int out_size, void* d_ws, size_t ws_size,
                              hipStream_t stream) {
  const float* x    = (const float*)d_in[0];  // [8, 8192]
  const float* w    = (const float*)d_in[1];  // [33591286] packed triangular
  const float* bias = (const float*)d_in[2];  // [8192]
  float* out = (float*)d_out;                 // [8, 8192]
  tri_linear_kernel<<<N / ROWS, THREADS, 0, stream>>>(x, w, bias, out);
}